// Round 2
// baseline (51.473 us; speedup 1.0000x reference)
//
#include <hip/hip_runtime.h>
#include <math.h>

// Problem constants
#define B_SZ   8192
#define D_IN   512
#define M0_N   128
#define M1_N   128
#define K_TOP  8
#define H_DIM  128
#define OUT_N  2

// ws header layout (ints), written by route_kernel:
// [0..1]    idx_out (2 selected layer-1 modules)
// [2..17]   idx1[j*8+k] : top-8 layer-0 module ids feeding layer-1 module j
// [18..33]  mods0[16]   : deduped layer-0 module ids (-1 = empty slot)
// [34..161] map[128]    : layer-0 module id -> slot (-1 if unused)
// [162..289] idx0[s*8+k]: top-8 input dims of x for slot s
#define HDR_INTS 290

// ---------------------------------------------------------------------------
// Wave-parallel iterative top-k with jax.lax.top_k semantics:
// descending value, ties broken by lowest index.
template<int NCH>
__device__ __forceinline__ void wave_topk(const float* __restrict__ base,
                                          int stride, int k, int* out_idx,
                                          int lane) {
  float v[NCH];
#pragma unroll
  for (int t = 0; t < NCH; ++t) v[t] = base[(t * 64 + lane) * stride];
  for (int r = 0; r < k; ++r) {
    float bv = -INFINITY;
    int bd = 0x7fffffff;
#pragma unroll
    for (int t = 0; t < NCH; ++t) {
      if (v[t] > bv) { bv = v[t]; bd = t * 64 + lane; }
    }
#pragma unroll
    for (int m = 1; m < 64; m <<= 1) {
      float ov = __shfl_xor(bv, m, 64);
      int   od = __shfl_xor(bd, m, 64);
      if (ov > bv || (ov == bv && od < bd)) { bv = ov; bd = od; }
    }
    if (lane == 0) out_idx[r] = bd;
    if ((bd & 63) == lane) {
      const int tw = bd >> 6;
#pragma unroll
      for (int tt = 0; tt < NCH; ++tt)
        if (tt == tw) v[tt] = -INFINITY;
    }
  }
}

// ---------------------------------------------------------------------------
__global__ __launch_bounds__(512)
void route_kernel(const int* __restrict__ task_id_p,
                  const float* __restrict__ emb0,
                  const float* __restrict__ emb1,
                  const float* __restrict__ emb_out,
                  int* __restrict__ hdr) {
  __shared__ int s_idx_out[2];
  __shared__ int s_idx1[16];
  __shared__ int s_mods0[16];
  __shared__ int s_map[128];
  __shared__ int s_idx0[128];
  const int tid  = threadIdx.x;
  const int lane = tid & 63;
  const int wid  = tid >> 6;
  const int task = task_id_p[0];

  if (tid < 128) s_map[tid] = -1;
  __syncthreads();

  if (wid == 0)
    wave_topk<2>(emb_out + task * M1_N, 1, OUT_N, s_idx_out, lane);
  __syncthreads();

  if (wid < 2) {
    const int m1 = s_idx_out[wid];
    wave_topk<2>(emb1 + task * M0_N * M1_N + m1, M1_N, K_TOP,
                 s_idx1 + wid * 8, lane);
  }
  __syncthreads();

  if (tid == 0) {
    int cnt = 0;
    for (int e = 0; e < 16; ++e) {
      const int m = s_idx1[e];
      if (s_map[m] < 0) { s_map[m] = cnt; s_mods0[cnt++] = m; }
    }
    for (int s2 = cnt; s2 < 16; ++s2) s_mods0[s2] = -1;
  }
  __syncthreads();

  for (int s = wid; s < 16; s += 8) {
    const int m0 = s_mods0[s];
    if (m0 >= 0)
      wave_topk<8>(emb0 + task * D_IN * M0_N + m0, M0_N, K_TOP,
                   s_idx0 + s * 8, lane);
  }
  __syncthreads();

  if (tid < 2)                      hdr[tid]              = s_idx_out[tid];
  if (tid >= 64  && tid < 80)       hdr[2  + (tid - 64)]  = s_idx1[tid - 64];
  if (tid >= 128 && tid < 144)      hdr[18 + (tid - 128)] = s_mods0[tid - 128];
  if (tid >= 192 && tid < 320)      hdr[34 + (tid - 192)] = s_map[tid - 192];
  if (tid >= 320 && tid < 448)      hdr[162 + (tid - 320)] = s_idx0[tid - 320];
}

// ---------------------------------------------------------------------------
// Fused layer0 (16 live modules) + layer1 (2 modules) + sigmoid.
// Block = 256 threads = 16 rows x 16 h-groups; thread (r,g) owns hidden
// units {g*4..g*4+3} and {(g+16)*4..(g+16)*4+3}. Per-row reduce over g is a
// 4-step shfl_xor across the low 4 lane bits. Weights read straight from
// global (L2-broadcast; 80 KB hot working set) — keeps the LDS pipe nearly
// idle (only a 1 KB out0 tile + header copy).
__global__ __launch_bounds__(256)
void fused_kernel(const float* __restrict__ x,
                  const float* __restrict__ W1_0, const float* __restrict__ b1_0,
                  const float* __restrict__ W2_0, const float* __restrict__ b2_0,
                  const float* __restrict__ W1_1, const float* __restrict__ b1_1,
                  const float* __restrict__ W2_1, const float* __restrict__ b2_1,
                  const int* __restrict__ hdr, float* __restrict__ out) {
  __shared__ int   sH[HDR_INTS];
  __shared__ float tile[16 * 16];       // [slot][row]

  const int tid = threadIdx.x;
  const int r   = tid >> 4;             // 0..15 local row
  const int g   = tid & 15;             // 0..15 h-group
  for (int i = tid; i < HDR_INTS; i += 256) sH[i] = hdr[i];
  __syncthreads();

  const int row = blockIdx.x * 16 + r;
  const float* xr = x + (size_t)row * D_IN;

  // ---- layer 0: loop over live slots ----
  for (int s = 0; s < 16; ++s) {
    const int m0 = sH[18 + s];
    if (m0 < 0) continue;               // uniform across block
    const int* idx = sH + 162 + s * 8;

    float xv[8];
#pragma unroll
    for (int k = 0; k < 8; ++k) xv[k] = xr[idx[k]];

    const float* w1 = W1_0 + m0 * (K_TOP * H_DIM);
    float4 a0 = ((const float4*)(b1_0 + m0 * H_DIM))[g];
    float4 a1 = ((const float4*)(b1_0 + m0 * H_DIM))[g + 16];
#pragma unroll
    for (int k = 0; k < 8; ++k) {
      const float4 wA = ((const float4*)(w1 + k * H_DIM))[g];
      const float4 wB = ((const float4*)(w1 + k * H_DIM))[g + 16];
      a0.x = fmaf(xv[k], wA.x, a0.x); a0.y = fmaf(xv[k], wA.y, a0.y);
      a0.z = fmaf(xv[k], wA.z, a0.z); a0.w = fmaf(xv[k], wA.w, a0.w);
      a1.x = fmaf(xv[k], wB.x, a1.x); a1.y = fmaf(xv[k], wB.y, a1.y);
      a1.z = fmaf(xv[k], wB.z, a1.z); a1.w = fmaf(xv[k], wB.w, a1.w);
    }
    const float4 w2a = ((const float4*)(W2_0 + m0 * H_DIM))[g];
    const float4 w2b = ((const float4*)(W2_0 + m0 * H_DIM))[g + 16];
    float p = 0.f;
    p = fmaf(fmaxf(a0.x, 0.f), w2a.x, p);
    p = fmaf(fmaxf(a0.y, 0.f), w2a.y, p);
    p = fmaf(fmaxf(a0.z, 0.f), w2a.z, p);
    p = fmaf(fmaxf(a0.w, 0.f), w2a.w, p);
    p = fmaf(fmaxf(a1.x, 0.f), w2b.x, p);
    p = fmaf(fmaxf(a1.y, 0.f), w2b.y, p);
    p = fmaf(fmaxf(a1.z, 0.f), w2b.z, p);
    p = fmaf(fmaxf(a1.w, 0.f), w2b.w, p);
#pragma unroll
    for (int m = 1; m < 16; m <<= 1) p += __shfl_xor(p, m, 64);
    if (g == 0) tile[s * 16 + r] = p + b2_0[m0];
  }
  __syncthreads();

  // ---- layer 1 (2 modules) + sigmoid ----
#pragma unroll
  for (int j = 0; j < 2; ++j) {
    const int m1 = sH[j];
    float xv[8];
#pragma unroll
    for (int k = 0; k < 8; ++k) {
      const int slot = sH[34 + sH[2 + j * 8 + k]];
      xv[k] = tile[slot * 16 + r];
    }
    const float* w1 = W1_1 + m1 * (K_TOP * H_DIM);
    float4 a0 = ((const float4*)(b1_1 + m1 * H_DIM))[g];
    float4 a1 = ((const float4*)(b1_1 + m1 * H_DIM))[g + 16];
#pragma unroll
    for (int k = 0; k < 8; ++k) {
      const float4 wA = ((const float4*)(w1 + k * H_DIM))[g];
      const float4 wB = ((const float4*)(w1 + k * H_DIM))[g + 16];
      a0.x = fmaf(xv[k], wA.x, a0.x); a0.y = fmaf(xv[k], wA.y, a0.y);
      a0.z = fmaf(xv[k], wA.z, a0.z); a0.w = fmaf(xv[k], wA.w, a0.w);
      a1.x = fmaf(xv[k], wB.x, a1.x); a1.y = fmaf(xv[k], wB.y, a1.y);
      a1.z = fmaf(xv[k], wB.z, a1.z); a1.w = fmaf(xv[k], wB.w, a1.w);
    }
    const float4 w2a = ((const float4*)(W2_1 + m1 * H_DIM))[g];
    const float4 w2b = ((const float4*)(W2_1 + m1 * H_DIM))[g + 16];
    float p = 0.f;
    p = fmaf(fmaxf(a0.x, 0.f), w2a.x, p);
    p = fmaf(fmaxf(a0.y, 0.f), w2a.y, p);
    p = fmaf(fmaxf(a0.z, 0.f), w2a.z, p);
    p = fmaf(fmaxf(a0.w, 0.f), w2a.w, p);
    p = fmaf(fmaxf(a1.x, 0.f), w2b.x, p);
    p = fmaf(fmaxf(a1.y, 0.f), w2b.y, p);
    p = fmaf(fmaxf(a1.z, 0.f), w2b.z, p);
    p = fmaf(fmaxf(a1.w, 0.f), w2b.w, p);
#pragma unroll
    for (int m = 1; m < 16; m <<= 1) p += __shfl_xor(p, m, 64);
    if (g == 0) {
      const float val = p + b2_1[m1];
      out[(size_t)row * OUT_N + j] = 1.f / (1.f + __expf(-val));
    }
  }
}

// ---------------------------------------------------------------------------
extern "C" void kernel_launch(void* const* d_in, const int* in_sizes, int n_in,
                              void* d_out, int out_size, void* d_ws, size_t ws_size,
                              hipStream_t stream) {
  const float* x       = (const float*)d_in[0];
  const int*   task_id = (const int*)  d_in[1];
  const float* emb0    = (const float*)d_in[2];
  const float* emb1    = (const float*)d_in[3];
  const float* emb_out = (const float*)d_in[4];
  const float* W1_0    = (const float*)d_in[5];
  const float* b1_0    = (const float*)d_in[6];
  const float* W2_0    = (const float*)d_in[7];
  const float* b2_0    = (const float*)d_in[8];
  const float* W1_1    = (const float*)d_in[9];
  const float* b1_1    = (const float*)d_in[10];
  const float* W2_1    = (const float*)d_in[11];
  const float* b2_1    = (const float*)d_in[12];

  int*   hdr = (int*)d_ws;
  float* out = (float*)d_out;

  route_kernel<<<1, 512, 0, stream>>>(task_id, emb0, emb1, emb_out, hdr);
  fused_kernel<<<512, 256, 0, stream>>>(x, W1_0, b1_0, W2_0, b2_0,
                                        W1_1, b1_1, W2_1, b2_1, hdr, out);
}

// Round 3
// 33.732 us; speedup vs baseline: 1.5259x; 1.5259x over previous
//
#include <hip/hip_runtime.h>
#include <math.h>

// Problem constants
#define B_SZ   8192
#define D_IN   512
#define M0_N   128
#define M1_N   128
#define K_TOP  8
#define H_DIM  128

// ws layout (ints):
//   [0..1]       idx_out  (top-2 modules of emb_out)
//   [64..1087]   pre1[col*8+r] : top-8 of emb1[task][:,col], all 128 cols
//   [2048..3071] pre0[col*8+r] : top-8 of emb0[task][:,col], all 128 cols
// byte 16384:    out0t[16][8192] float — layer-0 outputs, slot-major

// ---------------------------------------------------------------------------
// Wave-parallel iterative top-k, jax.lax.top_k semantics (descending value,
// ties -> lowest index). NCH*64 candidates, out_idx written by lane 0.
template<int NCH>
__device__ __forceinline__ void wave_topk(const float* __restrict__ base,
                                          int stride, int k, int* out_idx,
                                          int lane) {
  float v[NCH];
#pragma unroll
  for (int t = 0; t < NCH; ++t) v[t] = base[(t * 64 + lane) * stride];
  for (int r = 0; r < k; ++r) {
    float bv = -INFINITY;
    int bd = 0x7fffffff;
#pragma unroll
    for (int t = 0; t < NCH; ++t) {
      if (v[t] > bv) { bv = v[t]; bd = t * 64 + lane; }
    }
#pragma unroll
    for (int m = 1; m < 64; m <<= 1) {
      float ov = __shfl_xor(bv, m, 64);
      int   od = __shfl_xor(bd, m, 64);
      if (ov > bv || (ov == bv && od < bd)) { bv = ov; bd = od; }
    }
    if (lane == 0) out_idx[r] = bd;
    if ((bd & 63) == lane) {
      const int tw = bd >> 6;
#pragma unroll
      for (int tt = 0; tt < NCH; ++tt)
        if (tt == tw) v[tt] = -INFINITY;
    }
  }
}

// ---------------------------------------------------------------------------
// Speculative routing: top-8 for ALL columns of emb1 and emb0 (the compute
// kernels pick the few they need). Block(0,0) wave 0 also does emb_out top-2.
__global__ __launch_bounds__(256)
void route_pre(const int* __restrict__ task_id_p,
               const float* __restrict__ emb0,
               const float* __restrict__ emb1,
               const float* __restrict__ emb_out,
               int* __restrict__ ws) {
  const int task = task_id_p[0];
  const int lane = threadIdx.x & 63;
  const int wid  = threadIdx.x >> 6;
  const int col  = blockIdx.x * 4 + wid;
  if (blockIdx.y == 0) {
    wave_topk<2>(emb1 + task * M0_N * M1_N + col, M1_N, K_TOP,
                 ws + 64 + col * 8, lane);
    if (blockIdx.x == 0 && wid == 0)
      wave_topk<2>(emb_out + task * M1_N, 1, 2, ws, lane);
  } else {
    wave_topk<8>(emb0 + task * D_IN * M0_N + col, M0_N, K_TOP,
                 ws + 2048 + col * 8, lane);
  }
}

// ---------------------------------------------------------------------------
// Layer 0: block = (slot s = j*8+k positional, 64 rows). Weights register-
// stationary (amortized over 4 rows/thread); x gathered cooperatively into a
// padded LDS tile. Thread (g=tid&15, rl=tid>>4): h-slice [g*8, g*8+8), rows
// rl*4..rl*4+3. Reduce over 16 g-lanes via shfl_xor(1,2,4,8).
__global__ __launch_bounds__(256, 2)
void layer0_kernel(const float* __restrict__ x,
                   const float* __restrict__ W1, const float* __restrict__ b1,
                   const float* __restrict__ W2, const float* __restrict__ b2,
                   const int* __restrict__ ws, float* __restrict__ out0t) {
  __shared__ int   s_m0;
  __shared__ int   s_idx[8];
  __shared__ float xt[64 * 12];          // [row][k], pad 12 -> 2-way max

  const int tid = threadIdx.x;
  const int s   = blockIdx.x;            // slot 0..15
  const int rowbase = blockIdx.y * 64;

  if (tid == 0) {
    const int m1 = ws[s >> 3];           // idx_out[j]
    s_m0 = ws[64 + m1 * 8 + (s & 7)];    // pre1[m1][k]
  }
  __syncthreads();
  const int m0 = s_m0;

  const int g  = tid & 15;
  const int rl = tid >> 4;

  // weights -> registers (held across the row loop)
  const float4* w1p = (const float4*)(W1 + (size_t)m0 * (K_TOP * H_DIM));
  float4 w1a[8], w1b[8];
#pragma unroll
  for (int k = 0; k < 8; ++k) {
    w1a[k] = w1p[k * 32 + 2 * g];
    w1b[k] = w1p[k * 32 + 2 * g + 1];
  }
  const float4 b1a = ((const float4*)(b1 + m0 * H_DIM))[2 * g];
  const float4 b1b = ((const float4*)(b1 + m0 * H_DIM))[2 * g + 1];
  const float4 w2a = ((const float4*)(W2 + m0 * H_DIM))[2 * g];
  const float4 w2b = ((const float4*)(W2 + m0 * H_DIM))[2 * g + 1];
  const float  b2v = b2[m0];

  if (tid < 8) s_idx[tid] = ws[2048 + m0 * 8 + tid];
  __syncthreads();

  // cooperative x gather: 8 cols x 64 rows
#pragma unroll
  for (int e = tid; e < 512; e += 256) {
    const int k = e >> 6, r = e & 63;
    xt[r * 12 + k] = x[(size_t)(rowbase + r) * D_IN + s_idx[k]];
  }
  __syncthreads();

  float acc[4];
#pragma unroll
  for (int i = 0; i < 4; ++i) {
    const int r = rl * 4 + i;
    const float4 xA = *(const float4*)&xt[r * 12];
    const float4 xB = *(const float4*)&xt[r * 12 + 4];
    const float xv[8] = {xA.x, xA.y, xA.z, xA.w, xB.x, xB.y, xB.z, xB.w};
    float4 h0 = b1a, h1 = b1b;
#pragma unroll
    for (int k = 0; k < 8; ++k) {
      h0.x = fmaf(xv[k], w1a[k].x, h0.x);
      h0.y = fmaf(xv[k], w1a[k].y, h0.y);
      h0.z = fmaf(xv[k], w1a[k].z, h0.z);
      h0.w = fmaf(xv[k], w1a[k].w, h0.w);
      h1.x = fmaf(xv[k], w1b[k].x, h1.x);
      h1.y = fmaf(xv[k], w1b[k].y, h1.y);
      h1.z = fmaf(xv[k], w1b[k].z, h1.z);
      h1.w = fmaf(xv[k], w1b[k].w, h1.w);
    }
    float p = 0.f;
    p = fmaf(fmaxf(h0.x, 0.f), w2a.x, p);
    p = fmaf(fmaxf(h0.y, 0.f), w2a.y, p);
    p = fmaf(fmaxf(h0.z, 0.f), w2a.z, p);
    p = fmaf(fmaxf(h0.w, 0.f), w2a.w, p);
    p = fmaf(fmaxf(h1.x, 0.f), w2b.x, p);
    p = fmaf(fmaxf(h1.y, 0.f), w2b.y, p);
    p = fmaf(fmaxf(h1.z, 0.f), w2b.z, p);
    p = fmaf(fmaxf(h1.w, 0.f), w2b.w, p);
    acc[i] = p;
  }
#pragma unroll
  for (int i = 0; i < 4; ++i) {
#pragma unroll
    for (int m = 1; m < 16; m <<= 1) acc[i] += __shfl_xor(acc[i], m, 64);
  }
  if (g == 0) {
    float4 o;
    o.x = acc[0] + b2v; o.y = acc[1] + b2v;
    o.z = acc[2] + b2v; o.w = acc[3] + b2v;
    *(float4*)&out0t[(size_t)s * B_SZ + rowbase + rl * 4] = o;
  }
}

// ---------------------------------------------------------------------------
// Layer 1: block = (module j, 64 rows). Inputs are the positional slots
// j*8+k of out0t (coalesced), fused bias + sigmoid epilogue.
__global__ __launch_bounds__(256, 2)
void layer1_kernel(const float* __restrict__ out0t,
                   const float* __restrict__ W1, const float* __restrict__ b1,
                   const float* __restrict__ W2, const float* __restrict__ b2,
                   const int* __restrict__ ws, float* __restrict__ out) {
  __shared__ int   s_m1;
  __shared__ float xt[64 * 12];

  const int tid = threadIdx.x;
  const int j   = blockIdx.x;            // 0..1
  const int rowbase = blockIdx.y * 64;

  if (tid == 0) s_m1 = ws[j];
  __syncthreads();
  const int m1 = s_m1;

  const int g  = tid & 15;
  const int rl = tid >> 4;

  const float4* w1p = (const float4*)(W1 + (size_t)m1 * (K_TOP * H_DIM));
  float4 w1a[8], w1b[8];
#pragma unroll
  for (int k = 0; k < 8; ++k) {
    w1a[k] = w1p[k * 32 + 2 * g];
    w1b[k] = w1p[k * 32 + 2 * g + 1];
  }
  const float4 b1a = ((const float4*)(b1 + m1 * H_DIM))[2 * g];
  const float4 b1b = ((const float4*)(b1 + m1 * H_DIM))[2 * g + 1];
  const float4 w2a = ((const float4*)(W2 + m1 * H_DIM))[2 * g];
  const float4 w2b = ((const float4*)(W2 + m1 * H_DIM))[2 * g + 1];
  const float  b2v = b2[m1];

  // coalesced stage of the 8 slot rows for this block
#pragma unroll
  for (int e = tid; e < 512; e += 256) {
    const int k = e >> 6, r = e & 63;
    xt[r * 12 + k] = out0t[(size_t)(j * 8 + k) * B_SZ + rowbase + r];
  }
  __syncthreads();

  float acc[4];
#pragma unroll
  for (int i = 0; i < 4; ++i) {
    const int r = rl * 4 + i;
    const float4 xA = *(const float4*)&xt[r * 12];
    const float4 xB = *(const float4*)&xt[r * 12 + 4];
    const float xv[8] = {xA.x, xA.y, xA.z, xA.w, xB.x, xB.y, xB.z, xB.w};
    float4 h0 = b1a, h1 = b1b;
#pragma unroll
    for (int k = 0; k < 8; ++k) {
      h0.x = fmaf(xv[k], w1a[k].x, h0.x);
      h0.y = fmaf(xv[k], w1a[k].y, h0.y);
      h0.z = fmaf(xv[k], w1a[k].z, h0.z);
      h0.w = fmaf(xv[k], w1a[k].w, h0.w);
      h1.x = fmaf(xv[k], w1b[k].x, h1.x);
      h1.y = fmaf(xv[k], w1b[k].y, h1.y);
      h1.z = fmaf(xv[k], w1b[k].z, h1.z);
      h1.w = fmaf(xv[k], w1b[k].w, h1.w);
    }
    float p = 0.f;
    p = fmaf(fmaxf(h0.x, 0.f), w2a.x, p);
    p = fmaf(fmaxf(h0.y, 0.f), w2a.y, p);
    p = fmaf(fmaxf(h0.z, 0.f), w2a.z, p);
    p = fmaf(fmaxf(h0.w, 0.f), w2a.w, p);
    p = fmaf(fmaxf(h1.x, 0.f), w2b.x, p);
    p = fmaf(fmaxf(h1.y, 0.f), w2b.y, p);
    p = fmaf(fmaxf(h1.z, 0.f), w2b.z, p);
    p = fmaf(fmaxf(h1.w, 0.f), w2b.w, p);
    acc[i] = p;
  }
#pragma unroll
  for (int i = 0; i < 4; ++i) {
#pragma unroll
    for (int m = 1; m < 16; m <<= 1) acc[i] += __shfl_xor(acc[i], m, 64);
  }
  if (g == 0) {
#pragma unroll
    for (int i = 0; i < 4; ++i) {
      const float v = acc[i] + b2v;
      out[(size_t)(rowbase + rl * 4 + i) * 2 + j] = 1.f / (1.f + __expf(-v));
    }
  }
}

// ---------------------------------------------------------------------------
extern "C" void kernel_launch(void* const* d_in, const int* in_sizes, int n_in,
                              void* d_out, int out_size, void* d_ws, size_t ws_size,
                              hipStream_t stream) {
  const float* x       = (const float*)d_in[0];
  const int*   task_id = (const int*)  d_in[1];
  const float* emb0    = (const float*)d_in[2];
  const float* emb1    = (const float*)d_in[3];
  const float* emb_out = (const float*)d_in[4];
  const float* W1_0    = (const float*)d_in[5];
  const float* b1_0    = (const float*)d_in[6];
  const float* W2_0    = (const float*)d_in[7];
  const float* b2_0    = (const float*)d_in[8];
  const float* W1_1    = (const float*)d_in[9];
  const float* b1_1    = (const float*)d_in[10];
  const float* W2_1    = (const float*)d_in[11];
  const float* b2_1    = (const float*)d_in[12];

  int*   ws    = (int*)d_ws;
  float* out0t = (float*)((char*)d_ws + 16384);
  float* out   = (float*)d_out;

  route_pre<<<dim3(32, 2), 256, 0, stream>>>(task_id, emb0, emb1, emb_out, ws);
  layer0_kernel<<<dim3(16, 128), 256, 0, stream>>>(x, W1_0, b1_0, W2_0, b2_0,
                                                   ws, out0t);
  layer1_kernel<<<dim3(2, 128), 256, 0, stream>>>(out0t, W1_1, b1_1, W2_1, b2_1,
                                                  ws, out);
}